// Round 1
// 92.754 us; speedup vs baseline: 1.0767x; 1.0767x over previous
//
#include <hip/hip_runtime.h>
#include <math.h>

#define BB 64
#define SQ 32
#define SD 256
#define HH 128
#define NQ (BB*SQ)   // 2048
#define ND (BB*SD)   // 16384
#define AG 8         // a's per scores block
#define DCHUNK 32    // rows per d prep block
#define NDBLK (ND/DCHUNK)   // 512 d prep blocks
#define PARTS (SD/DCHUNK)   // 8 partials per d batch

using short8  = __attribute__((ext_vector_type(8))) short;
using floatx4 = __attribute__((ext_vector_type(4))) float;

__device__ inline unsigned short f2bf(float x) {
  union { float f; unsigned u; } c; c.f = x;
  unsigned r = c.u + 0x7fffu + ((c.u >> 16) & 1u);  // RNE
  return (unsigned short)(r >> 16);
}

// ---------------------------------------------------------------------------
// Kernel 1 (fused, re-sharded): one pass over fp32 input computing
//   - per-row inv L2 norm
//   - mask-baked normalized bf16 rows (qng = qm*q/||q||, dng likewise)
//   - pairwise-sim ingredients: column sums + sum ||n_s||^2
// Grid: 64 q blocks (full 32-row batch -> finishes avgq) + 512 d blocks
// (32-row chunk -> emits partial colsum[128] + partial a2; combined in k3).
// 256 threads = 8 half-wave groups x 32 lanes; 4 rows/group, fully unrolled,
// rows prefetched up front so the 4 reduce chains overlap (was: 1 wave/SIMD
// with 32 serial dependent iterations on only 128 blocks).
// ---------------------------------------------------------------------------
__global__ __launch_bounds__(256) void prep_kernel(
    const float* __restrict__ qe, const float* __restrict__ de,
    const int* __restrict__ qmask, const int* __restrict__ dmask,
    unsigned short* __restrict__ qng, unsigned short* __restrict__ dng,
    float* __restrict__ avgq, float* __restrict__ dcol, float* __restrict__ da2) {
  __shared__ float colsum[8 * 128];   // [group][col]
  __shared__ float red[4];
  const int bid = blockIdx.x, tid = threadIdx.x;
  const int g = tid >> 5, c = tid & 31;

  const float* src; const int* msk; unsigned short* dst;
  if (bid < BB) {
    src = qe + (size_t)bid * SQ * HH; msk = qmask + bid * SQ;
    dst = qng + (size_t)bid * SQ * HH;
  } else {
    const int p = bid - BB;           // 0..511: flat 32-row chunk of d
    src = de + (size_t)p * DCHUNK * HH; msk = dmask + p * DCHUNK;
    dst = dng + (size_t)p * DCHUNK * HH;
  }

  // prefetch all 4 rows + masks (independent loads, breaks latency chains)
  float4 v[4];
#pragma unroll
  for (int i = 0; i < 4; i++)
    v[i] = ((const float4*)(src + (size_t)(g + 8 * i) * HH))[c];
  int m[4];
#pragma unroll
  for (int i = 0; i < 4; i++) m[i] = msk[g + 8 * i];

  float cs0 = 0.f, cs1 = 0.f, cs2 = 0.f, cs3 = 0.f;  // per-col partial sums
  float a2 = 0.f;                                    // partial sum ||n_s||^2
#pragma unroll
  for (int i = 0; i < 4; i++) {
    float ss = v[i].x*v[i].x + v[i].y*v[i].y + v[i].z*v[i].z + v[i].w*v[i].w;
#pragma unroll
    for (int off = 16; off; off >>= 1) ss += __shfl_xor(ss, off);  // 32-lane group
    float inv = 1.0f / fmaxf(sqrtf(ss), 1e-12f);
    float nx = v[i].x * inv, ny = v[i].y * inv, nz = v[i].z * inv, nw = v[i].w * inv;
    cs0 += nx; cs1 += ny; cs2 += nz; cs3 += nw;
    a2 += nx*nx + ny*ny + nz*nz + nw*nw;
    float mm = (float)m[i] * inv;
    ushort4 o;
    o.x = f2bf(v[i].x * mm); o.y = f2bf(v[i].y * mm);
    o.z = f2bf(v[i].z * mm); o.w = f2bf(v[i].w * mm);
    ((ushort4*)(dst + (size_t)(g + 8 * i) * HH))[c] = o;
  }
  // store col partials: contiguous float4 per lane -> conflict-free b128
  *(float4*)&colsum[g * 128 + c * 4] = make_float4(cs0, cs1, cs2, cs3);
  __syncthreads();

  if (bid < BB) {
    // full batch in-block: finish avgq = (||sum n||^2 - sum ||n||^2)/(S(S-1))
    float z = -a2;
    if (tid < 128) {
      float s = 0.f;
#pragma unroll
      for (int gg = 0; gg < 8; gg++) s += colsum[gg * 128 + tid];
      z += s * s;
    }
#pragma unroll
    for (int off = 32; off; off >>= 1) z += __shfl_xor(z, off);
    if ((tid & 63) == 0) red[tid >> 6] = z;
    __syncthreads();
    if (tid == 0)
      avgq[bid] = (red[0] + red[1] + red[2] + red[3]) * (1.0f / (SQ * (SQ - 1)));
  } else {
    // partial chunk: emit colsum vector (unsquared!) + a2 partial
    const int p = bid - BB;
    if (tid < 128) {
      float s = 0.f;
#pragma unroll
      for (int gg = 0; gg < 8; gg++) s += colsum[gg * 128 + tid];
      dcol[(size_t)p * 128 + tid] = s;
    }
    float z = a2;
#pragma unroll
    for (int off = 32; off; off >>= 1) z += __shfl_xor(z, off);
    if ((tid & 63) == 0) red[tid >> 6] = z;
    __syncthreads();
    if (tid == 0) da2[p] = red[0] + red[1] + red[2] + red[3];
  }
}

// ---------------------------------------------------------------------------
// Kernel 2 (UNCHANGED): scores[a,b] = max_{s,t} qng[a,s]·dng[b,t].
// Grid (BB, BB/AG) = (64,8) = 512 blocks, 2 blocks/CU (LDS 68KB).
// ---------------------------------------------------------------------------
__global__ __launch_bounds__(256, 2) void scores_kernel(
    const unsigned short* __restrict__ qng, const unsigned short* __restrict__ dng,
    float* __restrict__ scores) {
  __shared__ __align__(16) unsigned short dt[SD][HH + 8];
  const int tid = threadIdx.x;
  const int bb = blockIdx.x;
  const int m0 = blockIdx.y * AG * SQ;         // 256 q-rows per block
  const int wave = tid >> 6, lane = tid & 63;
  const int quad = lane >> 4, l16 = lane & 15;

  // stage d tile: 4096 chunks x 16B, fully coalesced (1KB per wave-instr).
#pragma unroll
  for (int i = 0; i < 16; i++) {
    int idx = i * 256 + tid;
    int row = idx >> 4, c = idx & 15;
    uint4 v = ((const uint4*)(dng + (size_t)(bb * SD + row) * HH))[c];
    *(uint4*)&dt[row][c * 8] = v;
  }

  // A fragments: wave's 64 M-rows, full K=128. 16 x short8 = 64 VGPRs.
  short8 af[4][4];
  const unsigned short* qbase = qng + (size_t)(m0 + wave * 64 + l16) * HH + quad * 8;
#pragma unroll
  for (int mi = 0; mi < 4; mi++)
#pragma unroll
    for (int kc = 0; kc < 4; kc++)
      af[mi][kc] = *(const short8*)(qbase + mi * 16 * HH + kc * 32);

  __syncthreads();

  float m0v = -1e30f, m1v = -1e30f;   // per-a maxima (a = blockIdx.y*AG + wave*2 + {0,1})
  const floatx4 zero = {0.f, 0.f, 0.f, 0.f};

#pragma unroll
  for (int nc = 0; nc < 4; nc++) {
    floatx4 acc[4][4];
#pragma unroll
    for (int mi = 0; mi < 4; mi++)
#pragma unroll
      for (int ni = 0; ni < 4; ni++) acc[mi][ni] = zero;
#pragma unroll
    for (int kc = 0; kc < 4; kc++) {
      short8 bf[4];
#pragma unroll
      for (int ni = 0; ni < 4; ni++)
        bf[ni] = *(const short8*)&dt[nc * 64 + ni * 16 + l16][kc * 32 + quad * 8];
#pragma unroll
      for (int mi = 0; mi < 4; mi++)
#pragma unroll
        for (int ni = 0; ni < 4; ni++)
          acc[mi][ni] = __builtin_amdgcn_mfma_f32_16x16x32_bf16(af[mi][kc], bf[ni], acc[mi][ni], 0, 0, 0);
    }
#pragma unroll
    for (int mi = 0; mi < 4; mi++) {
      float mm = -1e30f;
#pragma unroll
      for (int ni = 0; ni < 4; ni++)
#pragma unroll
        for (int r = 0; r < 4; r++) mm = fmaxf(mm, acc[mi][ni][r]);
      if (mi < 2) m0v = fmaxf(m0v, mm); else m1v = fmaxf(m1v, mm);
    }
  }
#pragma unroll
  for (int off = 32; off; off >>= 1) {
    m0v = fmaxf(m0v, __shfl_xor(m0v, off));
    m1v = fmaxf(m1v, __shfl_xor(m1v, off));
  }
  if (lane == 0) {
    int a = blockIdx.y * AG + wave * 2;
    scores[(size_t)a * BB + bb]       = m0v;
    scores[(size_t)(a + 1) * BB + bb] = m1v;
  }
}

// ---------------------------------------------------------------------------
// Kernel 3 (widened to 256 threads): combine d partials -> avgd, then
// loss = mean_a(lse_a - diag_a) + mean(avgq) + mean(avgd).
// Phase A: 4 threads/batch reduce dcol[8 parts][128] -> ||colsum||^2 - a2.
// Phase B: 4 threads/row CE (max + expsum over 16 cols each, quad shuffles).
// ---------------------------------------------------------------------------
__global__ __launch_bounds__(256) void final_kernel(
    const float* __restrict__ scores, const float* __restrict__ avgq,
    const float* __restrict__ dcol, const float* __restrict__ da2,
    float* __restrict__ out) {
  __shared__ float savgd[BB];
  __shared__ float sred[BB];
  const int tid = threadIdx.x;
  const int b = tid >> 2, j = tid & 3;   // 4 threads per batch/row, quad-aligned

  // Phase A: avgd[b] = (sum_c (sum_p dcol[p][c])^2 - sum_p a2[p]) / (Sd(Sd-1))
  float csq = 0.f;
#pragma unroll
  for (int cc = 0; cc < 32; cc += 4) {
    float4 s = make_float4(0.f, 0.f, 0.f, 0.f);
#pragma unroll
    for (int p = 0; p < PARTS; p++) {
      const float4 t = *(const float4*)(dcol + (size_t)(b * PARTS + p) * 128 + j * 32 + cc);
      s.x += t.x; s.y += t.y; s.z += t.z; s.w += t.w;
    }
    csq += s.x*s.x + s.y*s.y + s.z*s.z + s.w*s.w;
  }
  csq += __shfl_xor(csq, 1);
  csq += __shfl_xor(csq, 2);
  if (j == 0) {
    float a2s = 0.f;
#pragma unroll
    for (int p = 0; p < PARTS; p++) a2s += da2[b * PARTS + p];
    savgd[b] = (csq - a2s) * (1.0f / ((float)SD * (float)(SD - 1)));
  }
  __syncthreads();

  // Phase B: CE. Row a = b; thread j handles cols [j*16, j*16+16).
  const int a = b;
  float r[16];
  const float4* pr = (const float4*)(scores + (size_t)a * BB + j * 16);
  float mx = -1e30f;
#pragma unroll
  for (int i = 0; i < 4; i++) {
    float4 v = pr[i];
    r[i*4+0] = v.x; r[i*4+1] = v.y; r[i*4+2] = v.z; r[i*4+3] = v.w;
    mx = fmaxf(mx, fmaxf(fmaxf(v.x, v.y), fmaxf(v.z, v.w)));
  }
  mx = fmaxf(mx, __shfl_xor(mx, 1));
  mx = fmaxf(mx, __shfl_xor(mx, 2));
  float sum = 0.f;
#pragma unroll
  for (int k = 0; k < 16; k++) sum += expf(r[k] - mx);
  sum += __shfl_xor(sum, 1);
  sum += __shfl_xor(sum, 2);
  if (j == 0) {
    float diag = scores[(size_t)a * BB + a];
    sred[a] = logf(sum) + mx - diag + avgq[a] + savgd[a];
  }
  __syncthreads();
  if (tid < 64) {
    float v = sred[tid];
#pragma unroll
    for (int off = 32; off; off >>= 1) v += __shfl_xor(v, off);
    if (tid == 0) out[0] = v * (1.0f / 64.0f);
  }
}

// ---------------------------------------------------------------------------
extern "C" void kernel_launch(void* const* d_in, const int* in_sizes, int n_in,
                              void* d_out, int out_size, void* d_ws, size_t ws_size,
                              hipStream_t stream) {
  const float* qe   = (const float*)d_in[0];
  const float* de   = (const float*)d_in[1];
  const int* qmask  = (const int*)d_in[2];
  const int* dmask  = (const int*)d_in[3];
  float* out = (float*)d_out;
  char* ws = (char*)d_ws;

  float* scores = (float*)(ws);                  // 4096 f = 16384 B
  float* avgq   = (float*)(ws + 16384);          // 64 f
  float* da2    = (float*)(ws + 16640);          // 512 f = 2048 B
  float* dcol   = (float*)(ws + 20480);          // 512*128 f = 262144 B
  unsigned short* qng = (unsigned short*)(ws + 294912);   // 2048*128 bf16 (mask-baked)
  unsigned short* dng = (unsigned short*)(ws + 819200);   // 16384*128 bf16 (mask-baked)

  prep_kernel<<<BB + NDBLK, 256, 0, stream>>>(qe, de, qmask, dmask, qng, dng, avgq, dcol, da2);
  scores_kernel<<<dim3(BB, BB / AG), 256, 0, stream>>>(qng, dng, scores);
  final_kernel<<<1, 256, 0, stream>>>(scores, avgq, dcol, da2, out);
}

// Round 2
// 91.691 us; speedup vs baseline: 1.0892x; 1.0116x over previous
//
#include <hip/hip_runtime.h>
#include <math.h>

#define BB 64
#define SQ 32
#define SD 256
#define HH 128
#define NQ (BB*SQ)   // 2048
#define ND (BB*SD)   // 16384
#define AG 8         // a's per scores block
#define DCHUNK 32    // rows per d prep block
#define NDBLK (ND/DCHUNK)   // 512 d prep blocks
#define PARTS (SD/DCHUNK)   // 8 partials per d batch

using short8  = __attribute__((ext_vector_type(8))) short;
using floatx4 = __attribute__((ext_vector_type(4))) float;

__device__ inline unsigned short f2bf(float x) {
  union { float f; unsigned u; } c; c.f = x;
  unsigned r = c.u + 0x7fffu + ((c.u >> 16) & 1u);  // RNE
  return (unsigned short)(r >> 16);
}

// ---------------------------------------------------------------------------
// Kernel 1 (fused, re-sharded): one pass over fp32 input computing
//   - per-row inv L2 norm
//   - mask-baked normalized bf16 rows (qng = qm*q/||q||, dng likewise)
//   - pairwise-sim ingredients: column sums + sum ||n_s||^2
// Grid: 64 q blocks (full batch -> finishes avgq) + 512 d 32-row chunks
// (emit partial colsum[128] + partial a2; combined inside scores_kernel).
// Block 0 also zeroes the completion counter for kernel 2's last-block CE.
// ---------------------------------------------------------------------------
__global__ __launch_bounds__(256) void prep_kernel(
    const float* __restrict__ qe, const float* __restrict__ de,
    const int* __restrict__ qmask, const int* __restrict__ dmask,
    unsigned short* __restrict__ qng, unsigned short* __restrict__ dng,
    float* __restrict__ avgq, float* __restrict__ dcol, float* __restrict__ da2,
    unsigned int* __restrict__ cnt) {
  __shared__ float colsum[8 * 128];   // [group][col]
  __shared__ float red[4];
  const int bid = blockIdx.x, tid = threadIdx.x;
  const int g = tid >> 5, c = tid & 31;

  if (bid == 0 && tid == 0) *cnt = 0;   // re-poisoned each iter; re-arm

  const float* src; const int* msk; unsigned short* dst;
  if (bid < BB) {
    src = qe + (size_t)bid * SQ * HH; msk = qmask + bid * SQ;
    dst = qng + (size_t)bid * SQ * HH;
  } else {
    const int p = bid - BB;           // 0..511: flat 32-row chunk of d
    src = de + (size_t)p * DCHUNK * HH; msk = dmask + p * DCHUNK;
    dst = dng + (size_t)p * DCHUNK * HH;
  }

  // prefetch all 4 rows + masks (independent loads, breaks latency chains)
  float4 v[4];
#pragma unroll
  for (int i = 0; i < 4; i++)
    v[i] = ((const float4*)(src + (size_t)(g + 8 * i) * HH))[c];
  int m[4];
#pragma unroll
  for (int i = 0; i < 4; i++) m[i] = msk[g + 8 * i];

  float cs0 = 0.f, cs1 = 0.f, cs2 = 0.f, cs3 = 0.f;  // per-col partial sums
  float a2 = 0.f;                                    // partial sum ||n_s||^2
#pragma unroll
  for (int i = 0; i < 4; i++) {
    float ss = v[i].x*v[i].x + v[i].y*v[i].y + v[i].z*v[i].z + v[i].w*v[i].w;
#pragma unroll
    for (int off = 16; off; off >>= 1) ss += __shfl_xor(ss, off);  // 32-lane group
    float inv = 1.0f / fmaxf(sqrtf(ss), 1e-12f);
    float nx = v[i].x * inv, ny = v[i].y * inv, nz = v[i].z * inv, nw = v[i].w * inv;
    cs0 += nx; cs1 += ny; cs2 += nz; cs3 += nw;
    a2 += nx*nx + ny*ny + nz*nz + nw*nw;
    float mm = (float)m[i] * inv;
    ushort4 o;
    o.x = f2bf(v[i].x * mm); o.y = f2bf(v[i].y * mm);
    o.z = f2bf(v[i].z * mm); o.w = f2bf(v[i].w * mm);
    ((ushort4*)(dst + (size_t)(g + 8 * i) * HH))[c] = o;
  }
  // store col partials: contiguous float4 per lane -> conflict-free b128
  *(float4*)&colsum[g * 128 + c * 4] = make_float4(cs0, cs1, cs2, cs3);
  __syncthreads();

  if (bid < BB) {
    // full batch in-block: finish avgq = (||sum n||^2 - sum ||n||^2)/(S(S-1))
    float z = -a2;
    if (tid < 128) {
      float s = 0.f;
#pragma unroll
      for (int gg = 0; gg < 8; gg++) s += colsum[gg * 128 + tid];
      z += s * s;
    }
#pragma unroll
    for (int off = 32; off; off >>= 1) z += __shfl_xor(z, off);
    if ((tid & 63) == 0) red[tid >> 6] = z;
    __syncthreads();
    if (tid == 0)
      avgq[bid] = (red[0] + red[1] + red[2] + red[3]) * (1.0f / (SQ * (SQ - 1)));
  } else {
    // partial chunk: emit colsum vector (unsquared!) + a2 partial
    const int p = bid - BB;
    if (tid < 128) {
      float s = 0.f;
#pragma unroll
      for (int gg = 0; gg < 8; gg++) s += colsum[gg * 128 + tid];
      dcol[(size_t)p * 128 + tid] = s;
    }
    float z = a2;
#pragma unroll
    for (int off = 32; off; off >>= 1) z += __shfl_xor(z, off);
    if ((tid & 63) == 0) red[tid >> 6] = z;
    __syncthreads();
    if (tid == 0) da2[p] = red[0] + red[1] + red[2] + red[3];
  }
}

// ---------------------------------------------------------------------------
// Kernel 2: scores[a,b] = max_{s,t} qng[a,s]·dng[b,t] (masks pre-baked),
// PLUS fused epilogues:
//   - blocks with blockIdx.y==0 combine dcol/da2 partials -> avgd[bb]
//   - last-finishing block (device-scope counter) runs the CE reduction
//     and writes the final loss (replaces the old 1-block third kernel).
// Grid (BB, BB/AG) = (64,8) = 512 blocks, 2 blocks/CU (LDS ~70KB).
// ---------------------------------------------------------------------------
__global__ __launch_bounds__(256, 2) void scores_kernel(
    const unsigned short* __restrict__ qng, const unsigned short* __restrict__ dng,
    float* __restrict__ scores, const float* __restrict__ avgq,
    const float* __restrict__ dcol, const float* __restrict__ da2,
    float* __restrict__ avgd, unsigned int* __restrict__ cnt,
    float* __restrict__ out) {
  __shared__ __align__(16) unsigned short dt[SD][HH + 8];
  __shared__ float zred[4];
  __shared__ float sred[BB];
  __shared__ int amLast;
  const int tid = threadIdx.x;
  const int bb = blockIdx.x;
  const int m0 = blockIdx.y * AG * SQ;         // 256 q-rows per block
  const int wave = tid >> 6, lane = tid & 63;
  const int quad = lane >> 4, l16 = lane & 15;

  // stage d tile: 4096 chunks x 16B, fully coalesced (1KB per wave-instr).
#pragma unroll
  for (int i = 0; i < 16; i++) {
    int idx = i * 256 + tid;
    int row = idx >> 4, c = idx & 15;
    uint4 v = ((const uint4*)(dng + (size_t)(bb * SD + row) * HH))[c];
    *(uint4*)&dt[row][c * 8] = v;
  }

  // A fragments: wave's 64 M-rows, full K=128. 16 x short8 = 64 VGPRs.
  short8 af[4][4];
  const unsigned short* qbase = qng + (size_t)(m0 + wave * 64 + l16) * HH + quad * 8;
#pragma unroll
  for (int mi = 0; mi < 4; mi++)
#pragma unroll
    for (int kc = 0; kc < 4; kc++)
      af[mi][kc] = *(const short8*)(qbase + mi * 16 * HH + kc * 32);

  __syncthreads();

  float m0v = -1e30f, m1v = -1e30f;   // per-a maxima (a = blockIdx.y*AG + wave*2 + {0,1})
  const floatx4 zero = {0.f, 0.f, 0.f, 0.f};

#pragma unroll
  for (int nc = 0; nc < 4; nc++) {
    floatx4 acc[4][4];
#pragma unroll
    for (int mi = 0; mi < 4; mi++)
#pragma unroll
      for (int ni = 0; ni < 4; ni++) acc[mi][ni] = zero;
#pragma unroll
    for (int kc = 0; kc < 4; kc++) {
      short8 bf[4];
#pragma unroll
      for (int ni = 0; ni < 4; ni++)
        bf[ni] = *(const short8*)&dt[nc * 64 + ni * 16 + l16][kc * 32 + quad * 8];
#pragma unroll
      for (int mi = 0; mi < 4; mi++)
#pragma unroll
        for (int ni = 0; ni < 4; ni++)
          acc[mi][ni] = __builtin_amdgcn_mfma_f32_16x16x32_bf16(af[mi][kc], bf[ni], acc[mi][ni], 0, 0, 0);
    }
#pragma unroll
    for (int mi = 0; mi < 4; mi++) {
      float mm = -1e30f;
#pragma unroll
      for (int ni = 0; ni < 4; ni++)
#pragma unroll
        for (int r = 0; r < 4; r++) mm = fmaxf(mm, acc[mi][ni][r]);
      if (mi < 2) m0v = fmaxf(m0v, mm); else m1v = fmaxf(m1v, mm);
    }
  }
#pragma unroll
  for (int off = 32; off; off >>= 1) {
    m0v = fmaxf(m0v, __shfl_xor(m0v, off));
    m1v = fmaxf(m1v, __shfl_xor(m1v, off));
  }
  if (lane == 0) {
    int a = blockIdx.y * AG + wave * 2;
    scores[(size_t)a * BB + bb]       = m0v;
    scores[(size_t)(a + 1) * BB + bb] = m1v;
  }

  // -- fused avgd: 64 designated blocks combine their batch's dcol partials --
  if (blockIdx.y == 0) {
    float z = 0.f;
    if (tid < 128) {
      float s = 0.f;
#pragma unroll
      for (int p = 0; p < PARTS; p++) s += dcol[(size_t)(bb * PARTS + p) * 128 + tid];
      z = s * s;
    }
#pragma unroll
    for (int off = 32; off; off >>= 1) z += __shfl_xor(z, off);
    if (lane == 0) zred[wave] = z;
    __syncthreads();
    if (tid == 0) {
      float a2s = 0.f;
#pragma unroll
      for (int p = 0; p < PARTS; p++) a2s += da2[bb * PARTS + p];
      avgd[bb] = (zred[0] + zred[1] + zred[2] + zred[3] - a2s)
                 * (1.0f / ((float)SD * (float)(SD - 1)));
    }
  }

  // -- last-block-done: release our stores, count, last block runs the CE --
  __syncthreads();
  if (tid == 0) {
    __threadfence();                       // release: scores/avgd visible device-wide
    unsigned int old = atomicAdd(cnt, 1u); // device scope by default
    amLast = (old == (unsigned int)(gridDim.x * gridDim.y - 1));
  }
  __syncthreads();
  if (!amLast) return;
  __threadfence();                         // acquire: see all other blocks' stores

  // CE: 4 threads per row a; thread j handles cols [j*16, j*16+16).
  {
    const int a = tid >> 2, j = tid & 3;
    float r[16];
    const float4* pr = (const float4*)(scores + (size_t)a * BB + j * 16);
    float mx = -1e30f;
#pragma unroll
    for (int i = 0; i < 4; i++) {
      float4 v = pr[i];
      r[i*4+0] = v.x; r[i*4+1] = v.y; r[i*4+2] = v.z; r[i*4+3] = v.w;
      mx = fmaxf(mx, fmaxf(fmaxf(v.x, v.y), fmaxf(v.z, v.w)));
    }
    mx = fmaxf(mx, __shfl_xor(mx, 1));
    mx = fmaxf(mx, __shfl_xor(mx, 2));
    float sum = 0.f;
#pragma unroll
    for (int k = 0; k < 16; k++) sum += expf(r[k] - mx);
    sum += __shfl_xor(sum, 1);
    sum += __shfl_xor(sum, 2);
    if (j == 0) {
      float diag = scores[(size_t)a * BB + a];
      sred[a] = logf(sum) + mx - diag + avgq[a] + avgd[a];
    }
    __syncthreads();
    if (tid < 64) {
      float v = sred[tid];
#pragma unroll
      for (int off = 32; off; off >>= 1) v += __shfl_xor(v, off);
      if (tid == 0) out[0] = v * (1.0f / 64.0f);
    }
  }
}

// ---------------------------------------------------------------------------
extern "C" void kernel_launch(void* const* d_in, const int* in_sizes, int n_in,
                              void* d_out, int out_size, void* d_ws, size_t ws_size,
                              hipStream_t stream) {
  const float* qe   = (const float*)d_in[0];
  const float* de   = (const float*)d_in[1];
  const int* qmask  = (const int*)d_in[2];
  const int* dmask  = (const int*)d_in[3];
  float* out = (float*)d_out;
  char* ws = (char*)d_ws;

  float* scores     = (float*)(ws);                  // 4096 f = 16384 B
  float* avgq       = (float*)(ws + 16384);          // 64 f
  float* avgd       = (float*)(ws + 16640);          // 64 f
  float* da2        = (float*)(ws + 16896);          // 512 f = 2048 B -> ends 18944
  unsigned int* cnt = (unsigned int*)(ws + 19456);   // isolated cacheline
  float* dcol       = (float*)(ws + 20480);          // 512*128 f = 262144 B
  unsigned short* qng = (unsigned short*)(ws + 294912);   // 2048*128 bf16 (mask-baked)
  unsigned short* dng = (unsigned short*)(ws + 819200);   // 16384*128 bf16 (mask-baked)

  prep_kernel<<<BB + NDBLK, 256, 0, stream>>>(qe, de, qmask, dmask, qng, dng,
                                              avgq, dcol, da2, cnt);
  scores_kernel<<<dim3(BB, BB / AG), 256, 0, stream>>>(qng, dng, scores, avgq,
                                                       dcol, da2, avgd, cnt, out);
}